// Round 3
// baseline (540.668 us; speedup 1.0000x reference)
//
#include <hip/hip_runtime.h>
#include <cstdint>
#include <cstddef>

#define T_TOKENS 8192
#define K_DIM 4096
#define N_DIM 4096

using i32x4 = __attribute__((ext_vector_type(4))) int;

// async global->LDS DMA, 16 bytes per lane. LDS dst = firstlane(l) + lane*16.
__device__ __forceinline__ void glds16(const int8_t* g, int8_t* l) {
    __builtin_amdgcn_global_load_lds(
        (const __attribute__((address_space(1))) unsigned int*)g,
        (__attribute__((address_space(3))) unsigned int*)l, 16, 0, 0);
}

// ---------------------------------------------------------------------------
// Kernel 0: pack harness-delivered int32 weight (one int8 per int32 element)
// into a dense int8 [N][K] matrix.
// ---------------------------------------------------------------------------
__global__ __launch_bounds__(256) void pack_weight(const int* __restrict__ win,
                                                   int8_t* __restrict__ wout) {
    const int idx = blockIdx.x * 256 + threadIdx.x;  // one dword (4 int8) out
    const i32x4 v = reinterpret_cast<const i32x4*>(win)[idx];
    uint32_t pk = (uint32_t)(v.x & 255) | ((uint32_t)(v.y & 255) << 8) |
                  ((uint32_t)(v.z & 255) << 16) | ((uint32_t)(v.w & 255) << 24);
    reinterpret_cast<int*>(wout)[idx] = (int)pk;
}

// ---------------------------------------------------------------------------
// Kernel 1: per-token dynamic quantization (one 256-thread block per token).
// q = clip(rint(x / (absmax/127)), -127, 127); store int8 row + scale.
// ---------------------------------------------------------------------------
__global__ __launch_bounds__(256) void quant_rows(const float* __restrict__ x,
                                                  int8_t* __restrict__ qx,
                                                  float* __restrict__ xscale) {
    const int t = blockIdx.x;
    const int tid = threadIdx.x;
    const float4* row = reinterpret_cast<const float4*>(x + (size_t)t * K_DIM);

    float4 v[4];
    float amax = 0.0f;
#pragma unroll
    for (int i = 0; i < 4; ++i) {
        v[i] = row[i * 256 + tid];
        amax = fmaxf(amax, fabsf(v[i].x));
        amax = fmaxf(amax, fabsf(v[i].y));
        amax = fmaxf(amax, fabsf(v[i].z));
        amax = fmaxf(amax, fabsf(v[i].w));
    }
#pragma unroll
    for (int off = 32; off > 0; off >>= 1)
        amax = fmaxf(amax, __shfl_xor(amax, off));

    __shared__ float red[4];
    if ((tid & 63) == 0) red[tid >> 6] = amax;
    __syncthreads();
    amax = fmaxf(fmaxf(red[0], red[1]), fmaxf(red[2], red[3]));

    const float scale = fmaxf(amax, 1e-30f) * (1.0f / 127.0f);
    if (tid == 0) xscale[t] = scale;

    int* qrow = reinterpret_cast<int*>(qx + (size_t)t * K_DIM);
#pragma unroll
    for (int i = 0; i < 4; ++i) {
        int q0 = (int)fminf(fmaxf(rintf(v[i].x / scale), -127.0f), 127.0f);
        int q1 = (int)fminf(fmaxf(rintf(v[i].y / scale), -127.0f), 127.0f);
        int q2 = (int)fminf(fmaxf(rintf(v[i].z / scale), -127.0f), 127.0f);
        int q3 = (int)fminf(fmaxf(rintf(v[i].w / scale), -127.0f), 127.0f);
        uint32_t pk = (uint32_t)(q0 & 255) | ((uint32_t)(q1 & 255) << 8) |
                      ((uint32_t)(q2 & 255) << 16) | ((uint32_t)(q3 & 255) << 24);
        qrow[i * 256 + tid] = (int)pk;
    }
}

// ---------------------------------------------------------------------------
// Kernel 2: int8 GEMM + dequant epilogue.
// 128x128 tile, BK=64, 4 waves 2x2, each wave 4x4 MFMAs mfma_i32_16x16x64_i8.
//
// LDS is FRAGMENT-MAJOR: group g (16 rows) stored as [g][quad][l16] 16B
// chunks, so As element (row = g*16 + l16, kchunk = quad) lives at byte
// offset (g*64 + quad*16 + l16)*16.  Consequences:
//  - global_load_lds: wave w's 64 lanes fill group g=w (and g=w+4)
//    contiguously in lane order (DMA requirement satisfied).
//  - fragment read af = As4[g*64 + lane]: whole wave reads contiguous 1KB,
//    sequential 16B/lane -> zero bank conflicts.
// C/D: col=lane&15, row=(lane>>4)*4+reg.
// ---------------------------------------------------------------------------
__global__ __launch_bounds__(256) void int8_gemm(const int8_t* __restrict__ qx,
                                                 const int8_t* __restrict__ w,
                                                 const float* __restrict__ xscale,
                                                 const float* __restrict__ wscale,
                                                 const float* __restrict__ bias,
                                                 float* __restrict__ out) {
    __shared__ int8_t As[128 * 64];
    __shared__ int8_t Bs[128 * 64];

    const int tid = threadIdx.x;
    const int lane = tid & 63;
    const int wave = tid >> 6;
    const int wr = wave >> 1;   // wave row (0..1) -> 64 tokens
    const int wc = wave & 1;    // wave col (0..1) -> 64 features
    const int l16 = lane & 15;
    const int quad = lane >> 4;

    const size_t a_row0 = (size_t)blockIdx.x * 128;
    const size_t b_row0 = (size_t)blockIdx.y * 128;

    // staging source: wave w, lane -> row (w*16 + l16), k-chunk quad
    const int8_t* agA = qx + (a_row0 + wave * 16 + l16) * (size_t)K_DIM + quad * 16;
    const int8_t* agB = agA + (size_t)64 * K_DIM;   // groups w+4
    const int8_t* bgA = w + (b_row0 + wave * 16 + l16) * (size_t)K_DIM + quad * 16;
    const int8_t* bgB = bgA + (size_t)64 * K_DIM;

    // LDS dst (per-lane ptr; HW takes firstlane as base, adds lane*16)
    int8_t* ldsA0 = As + tid * 16;
    int8_t* ldsA1 = As + 4096 + tid * 16;
    int8_t* ldsB0 = Bs + tid * 16;
    int8_t* ldsB1 = Bs + 4096 + tid * 16;

    i32x4* As4 = reinterpret_cast<i32x4*>(As);
    i32x4* Bs4 = reinterpret_cast<i32x4*>(Bs);

    i32x4 acc[4][4] = {};

    for (int k0 = 0; k0 < K_DIM; k0 += 64) {
        __syncthreads();  // prior iter's LDS reads done
        glds16(agA + k0, ldsA0);
        glds16(agB + k0, ldsA1);
        glds16(bgA + k0, ldsB0);
        glds16(bgB + k0, ldsB1);
        __syncthreads();  // drains vmcnt + barrier -> tiles visible

        i32x4 af[4], bf[4];
#pragma unroll
        for (int i = 0; i < 4; ++i) {
            af[i] = As4[(wr * 4 + i) * 64 + lane];
            bf[i] = Bs4[(wc * 4 + i) * 64 + lane];
        }
#pragma unroll
        for (int i = 0; i < 4; ++i)
#pragma unroll
            for (int j = 0; j < 4; ++j)
                acc[i][j] = __builtin_amdgcn_mfma_i32_16x16x64_i8(af[i], bf[j], acc[i][j], 0, 0, 0);
    }

    // epilogue: dequant + bias (C/D: col=l16, row=quad*4+r)
#pragma unroll
    for (int j = 0; j < 4; ++j) {
        const int n = (int)b_row0 + wc * 64 + j * 16 + l16;
        const float ws = wscale[n];
        const float bs = bias[n];
#pragma unroll
        for (int i = 0; i < 4; ++i) {
#pragma unroll
            for (int r = 0; r < 4; ++r) {
                const int t = (int)a_row0 + wr * 64 + i * 16 + quad * 4 + r;
                const float xs = xscale[t];
                out[(size_t)t * N_DIM + n] = (float)acc[i][j][r] * ws * xs + bs;
            }
        }
    }
}

extern "C" void kernel_launch(void* const* d_in, const int* in_sizes, int n_in,
                              void* d_out, int out_size, void* d_ws, size_t ws_size,
                              hipStream_t stream) {
    const float* x = (const float*)d_in[0];
    const int* w_i32 = (const int*)d_in[1];   // int8 ref input delivered as int32
    const float* wscale = (const float*)d_in[2];
    const float* bias = (const float*)d_in[3];
    float* out = (float*)d_out;

    // workspace: qx (32 MB) | xscale (32 KB) | packed weight (16 MB)
    int8_t* qx = (int8_t*)d_ws;
    float* xscale = (float*)((char*)d_ws + (size_t)T_TOKENS * K_DIM);
    int8_t* wpk = (int8_t*)((char*)d_ws + (size_t)T_TOKENS * K_DIM + 65536);

    pack_weight<<<(N_DIM * K_DIM / 4) / 256, 256, 0, stream>>>(w_i32, wpk);
    quant_rows<<<T_TOKENS, 256, 0, stream>>>(x, qx, xscale);

    dim3 grid(T_TOKENS / 128, N_DIM / 128);
    int8_gemm<<<grid, 256, 0, stream>>>(qx, wpk, xscale, wscale, bias, out);
}

// Round 4
// 533.185 us; speedup vs baseline: 1.0140x; 1.0140x over previous
//
#include <hip/hip_runtime.h>
#include <cstdint>
#include <cstddef>

#define T_TOKENS 8192
#define K_DIM 4096
#define N_DIM 4096

using i32x4 = __attribute__((ext_vector_type(4))) int;

// async global->LDS DMA, 16 bytes per lane. LDS dst = firstlane(l) + lane*16.
__device__ __forceinline__ void glds16(const int8_t* g, int8_t* l) {
    __builtin_amdgcn_global_load_lds(
        (const __attribute__((address_space(1))) unsigned int*)g,
        (__attribute__((address_space(3))) unsigned int*)l, 16, 0, 0);
}

// ---------------------------------------------------------------------------
// Kernel 0: pack harness-delivered int32 weight (one int8 per int32 element)
// into a dense int8 [N][K] matrix.
// ---------------------------------------------------------------------------
__global__ __launch_bounds__(256) void pack_weight(const int* __restrict__ win,
                                                   int8_t* __restrict__ wout) {
    const int idx = blockIdx.x * 256 + threadIdx.x;  // one dword (4 int8) out
    const i32x4 v = reinterpret_cast<const i32x4*>(win)[idx];
    uint32_t pk = (uint32_t)(v.x & 255) | ((uint32_t)(v.y & 255) << 8) |
                  ((uint32_t)(v.z & 255) << 16) | ((uint32_t)(v.w & 255) << 24);
    reinterpret_cast<int*>(wout)[idx] = (int)pk;
}

// ---------------------------------------------------------------------------
// Kernel 1: per-token dynamic quantization (one 256-thread block per token).
// q = clip(rint(x / (absmax/127)), -127, 127); store int8 row + scale.
// ---------------------------------------------------------------------------
__global__ __launch_bounds__(256) void quant_rows(const float* __restrict__ x,
                                                  int8_t* __restrict__ qx,
                                                  float* __restrict__ xscale) {
    const int t = blockIdx.x;
    const int tid = threadIdx.x;
    const float4* row = reinterpret_cast<const float4*>(x + (size_t)t * K_DIM);

    float4 v[4];
    float amax = 0.0f;
#pragma unroll
    for (int i = 0; i < 4; ++i) {
        v[i] = row[i * 256 + tid];
        amax = fmaxf(amax, fabsf(v[i].x));
        amax = fmaxf(amax, fabsf(v[i].y));
        amax = fmaxf(amax, fabsf(v[i].z));
        amax = fmaxf(amax, fabsf(v[i].w));
    }
#pragma unroll
    for (int off = 32; off > 0; off >>= 1)
        amax = fmaxf(amax, __shfl_xor(amax, off));

    __shared__ float red[4];
    if ((tid & 63) == 0) red[tid >> 6] = amax;
    __syncthreads();
    amax = fmaxf(fmaxf(red[0], red[1]), fmaxf(red[2], red[3]));

    const float scale = fmaxf(amax, 1e-30f) * (1.0f / 127.0f);
    if (tid == 0) xscale[t] = scale;

    int* qrow = reinterpret_cast<int*>(qx + (size_t)t * K_DIM);
#pragma unroll
    for (int i = 0; i < 4; ++i) {
        int q0 = (int)fminf(fmaxf(rintf(v[i].x / scale), -127.0f), 127.0f);
        int q1 = (int)fminf(fmaxf(rintf(v[i].y / scale), -127.0f), 127.0f);
        int q2 = (int)fminf(fmaxf(rintf(v[i].z / scale), -127.0f), 127.0f);
        int q3 = (int)fminf(fmaxf(rintf(v[i].w / scale), -127.0f), 127.0f);
        uint32_t pk = (uint32_t)(q0 & 255) | ((uint32_t)(q1 & 255) << 8) |
                      ((uint32_t)(q2 & 255) << 16) | ((uint32_t)(q3 & 255) << 24);
        qrow[i * 256 + tid] = (int)pk;
    }
}

// ---------------------------------------------------------------------------
// Kernel 2: int8 GEMM + dequant epilogue.
// 128x128 tile, BK=64, 4 waves 2x2, each wave 4x4 MFMAs mfma_i32_16x16x64_i8.
//
// LDS fragment-major layout (zero bank conflicts, DMA-compatible), and a
// DOUBLE-BUFFERED pipeline with raw s_barrier + fine-grained vmcnt:
//   issue DMA(tile k+1 -> buf^1)          // 8 outstanding
//   s_waitcnt vmcnt(4); s_barrier         // tile k landed, publish
//   ds_read frags(buf)                    // conflict-free contiguous 1KB/wave
//   s_waitcnt lgkmcnt(0); s_barrier       // all reads of buf done -> buf^1
//                                         //   safe to be overwritten next iter
//   16x mfma
// No __syncthreads in-loop => compiler never emits the vmcnt(0) drain; the
// prefetch stays in flight across the barrier (AITER-style, never wait to 0).
// C/D: col=lane&15, row=(lane>>4)*4+reg.
// ---------------------------------------------------------------------------
__global__ __launch_bounds__(256) void int8_gemm(const int8_t* __restrict__ qx,
                                                 const int8_t* __restrict__ w,
                                                 const float* __restrict__ xscale,
                                                 const float* __restrict__ wscale,
                                                 const float* __restrict__ bias,
                                                 float* __restrict__ out) {
    __shared__ int8_t As[2][128 * 64];
    __shared__ int8_t Bs[2][128 * 64];

    const int tid = threadIdx.x;
    const int lane = tid & 63;
    const int wave = tid >> 6;
    const int wr = wave >> 1;   // wave row (0..1) -> 64 tokens
    const int wc = wave & 1;    // wave col (0..1) -> 64 features
    const int l16 = lane & 15;
    const int quad = lane >> 4;

    const size_t a_row0 = (size_t)blockIdx.x * 128;
    const size_t b_row0 = (size_t)blockIdx.y * 128;

    // staging source: wave w, lane -> row (w*16 + l16), k-chunk quad
    const int8_t* agA = qx + (a_row0 + wave * 16 + l16) * (size_t)K_DIM + quad * 16;
    const int8_t* agB = agA + (size_t)64 * K_DIM;   // groups w+4
    const int8_t* bgA = w + (b_row0 + wave * 16 + l16) * (size_t)K_DIM + quad * 16;
    const int8_t* bgB = bgA + (size_t)64 * K_DIM;

    i32x4* As4 = reinterpret_cast<i32x4*>(&As[0][0]);
    i32x4* Bs4 = reinterpret_cast<i32x4*>(&Bs[0][0]);

    i32x4 acc[4][4] = {};

    // prologue: tile 0 -> buffer 0
    glds16(agA, &As[0][tid * 16]);
    glds16(agB, &As[0][4096 + tid * 16]);
    glds16(bgA, &Bs[0][tid * 16]);
    glds16(bgB, &Bs[0][4096 + tid * 16]);

    int cur = 0;
    for (int k0 = 0; k0 < K_DIM; k0 += 64) {
        const int nxt = cur ^ 1;
        const int kn = (k0 + 64 < K_DIM) ? k0 + 64 : 0;  // last iter: dummy wrap
        glds16(agA + kn, &As[nxt][tid * 16]);
        glds16(agB + kn, &As[nxt][4096 + tid * 16]);
        glds16(bgA + kn, &Bs[nxt][tid * 16]);
        glds16(bgB + kn, &Bs[nxt][4096 + tid * 16]);

        // wait only tile-k's 4 loads (keep 4 prefetch in flight), publish
        asm volatile("s_waitcnt vmcnt(4)\n\ts_barrier" ::: "memory");

        i32x4 af[4], bf[4];
#pragma unroll
        for (int i = 0; i < 4; ++i) {
            af[i] = As4[cur * 512 + (wr * 4 + i) * 64 + lane];
            bf[i] = Bs4[cur * 512 + (wc * 4 + i) * 64 + lane];
        }
        // all waves' reads of buf[cur] done before it can be overwritten
        asm volatile("s_waitcnt lgkmcnt(0)\n\ts_barrier" ::: "memory");

#pragma unroll
        for (int i = 0; i < 4; ++i)
#pragma unroll
            for (int j = 0; j < 4; ++j)
                acc[i][j] = __builtin_amdgcn_mfma_i32_16x16x64_i8(af[i], bf[j], acc[i][j], 0, 0, 0);
        cur = nxt;
    }
    // drain dummy prefetch so no DMA lands in a successor block's LDS
    asm volatile("s_waitcnt vmcnt(0)" ::: "memory");

    // epilogue: dequant + bias (C/D: col=l16, row=quad*4+r)
#pragma unroll
    for (int j = 0; j < 4; ++j) {
        const int n = (int)b_row0 + wc * 64 + j * 16 + l16;
        const float ws = wscale[n];
        const float bs = bias[n];
#pragma unroll
        for (int i = 0; i < 4; ++i) {
#pragma unroll
            for (int r = 0; r < 4; ++r) {
                const int t = (int)a_row0 + wr * 64 + i * 16 + quad * 4 + r;
                const float xs = xscale[t];
                out[(size_t)t * N_DIM + n] = (float)acc[i][j][r] * ws * xs + bs;
            }
        }
    }
}

extern "C" void kernel_launch(void* const* d_in, const int* in_sizes, int n_in,
                              void* d_out, int out_size, void* d_ws, size_t ws_size,
                              hipStream_t stream) {
    const float* x = (const float*)d_in[0];
    const int* w_i32 = (const int*)d_in[1];   // int8 ref input delivered as int32
    const float* wscale = (const float*)d_in[2];
    const float* bias = (const float*)d_in[3];
    float* out = (float*)d_out;

    // workspace: qx (32 MB) | xscale (32 KB) | packed weight (16 MB)
    int8_t* qx = (int8_t*)d_ws;
    float* xscale = (float*)((char*)d_ws + (size_t)T_TOKENS * K_DIM);
    int8_t* wpk = (int8_t*)((char*)d_ws + (size_t)T_TOKENS * K_DIM + 65536);

    pack_weight<<<(N_DIM * K_DIM / 4) / 256, 256, 0, stream>>>(w_i32, wpk);
    quant_rows<<<T_TOKENS, 256, 0, stream>>>(x, qx, xscale);

    dim3 grid(T_TOKENS / 128, N_DIM / 128);
    int8_gemm<<<grid, 256, 0, stream>>>(qx, wpk, xscale, wscale, bias, out);
}